// Round 5
// baseline (523.965 us; speedup 1.0000x reference)
//
#include <hip/hip_runtime.h>

typedef unsigned short u16;
typedef unsigned int u32;
typedef __bf16 bf16x8 __attribute__((ext_vector_type(8)));
typedef float f32x4 __attribute__((ext_vector_type(4)));
typedef u16 u16x8 __attribute__((ext_vector_type(8)));
typedef u16 u16x4 __attribute__((ext_vector_type(4)));

__device__ __forceinline__ u16 f2bf(float f) {
    union { float f; u32 i; } v; v.f = f;
    u32 x = v.i;
    u32 r = (x + 0x7fffu + ((x >> 16) & 1u)) >> 16;
    return (u16)r;
}
__device__ __forceinline__ float bf2f(u16 u) {
    union { u32 i; float f; } v; v.i = ((u32)u) << 16; return v.f;
}

__device__ __forceinline__ void gll16(const void* g, void* l) {
    __builtin_amdgcn_global_load_lds(
        (const __attribute__((address_space(1))) unsigned int*)(g),
        (__attribute__((address_space(3))) unsigned int*)(l),
        16, 0, 0);
}

// -------- weight transpose+convert: 4 matrices [512][512] fp32 -> bf16^T ---
__global__ __launch_bounds__(256) void transpose4(
    const float* __restrict__ s0, const float* __restrict__ s1,
    const float* __restrict__ s2, const float* __restrict__ s3,
    u16* __restrict__ d0, u16* __restrict__ d1,
    u16* __restrict__ d2, u16* __restrict__ d3)
{
    int bx = blockIdx.x;
    int mat = bx >> 8;
    int tile = bx & 255;
    int tx = (tile & 15) * 32;
    int ty = (tile >> 4) * 32;
    const float* src = (mat == 0) ? s0 : (mat == 1) ? s1 : (mat == 2) ? s2 : s3;
    u16* dst = (mat == 0) ? d0 : (mat == 1) ? d1 : (mat == 2) ? d2 : d3;

    __shared__ u16 tl[32][33];
    int col = threadIdx.x & 31;
    int r8  = threadIdx.x >> 5;
    #pragma unroll
    for (int k = 0; k < 4; ++k) {
        int rr = r8 + k * 8;
        tl[rr][col] = f2bf(src[(ty + rr) * 512 + tx + col]);
    }
    __syncthreads();
    #pragma unroll
    for (int k = 0; k < 4; ++k) {
        int rr = r8 + k * 8;
        dst[(tx + rr) * 512 + ty + col] = tl[col][rr];
    }
}

// -------- LayerNorm over H=512, one wave per row; out bf16 -----------------
__global__ __launch_bounds__(256) void ln_f32(
    const float* __restrict__ x, const float* __restrict__ g,
    const float* __restrict__ b, u16* __restrict__ y, int rows)
{
    int gid = blockIdx.x * blockDim.x + threadIdx.x;
    int row = gid >> 6;
    int lane = gid & 63;
    if (row >= rows) return;

    const float* xr = x + (size_t)row * 512 + lane * 8;
    float4 a0 = *(const float4*)xr;
    float4 a1 = *(const float4*)(xr + 4);
    float f[8] = {a0.x, a0.y, a0.z, a0.w, a1.x, a1.y, a1.z, a1.w};
    float s = 0.f, s2 = 0.f;
    #pragma unroll
    for (int e = 0; e < 8; ++e) { s += f[e]; s2 += f[e] * f[e]; }
    #pragma unroll
    for (int o = 32; o > 0; o >>= 1) { s += __shfl_xor(s, o); s2 += __shfl_xor(s2, o); }
    float mean = s * (1.0f / 512.0f);
    float var  = s2 * (1.0f / 512.0f) - mean * mean;
    float rstd = rsqrtf(var + 1e-5f);

    float4 g0 = *(const float4*)(g + lane * 8);
    float4 g1 = *(const float4*)(g + lane * 8 + 4);
    float4 b0 = *(const float4*)(b + lane * 8);
    float4 b1 = *(const float4*)(b + lane * 8 + 4);
    float gg[8] = {g0.x, g0.y, g0.z, g0.w, g1.x, g1.y, g1.z, g1.w};
    float bb[8] = {b0.x, b0.y, b0.z, b0.w, b1.x, b1.y, b1.z, b1.w};
    u16x8 ov;
    #pragma unroll
    for (int e = 0; e < 8; ++e)
        ov[e] = f2bf((f[e] - mean) * rstd * gg[e] + bb[e]);
    *(u16x8*)(y + (size_t)row * 512 + lane * 8) = ov;
}

__global__ __launch_bounds__(256) void ln_b16(
    const u16* __restrict__ x, const float* __restrict__ g,
    const float* __restrict__ b, u16* __restrict__ y, int rows)
{
    int gid = blockIdx.x * blockDim.x + threadIdx.x;
    int row = gid >> 6;
    int lane = gid & 63;
    if (row >= rows) return;

    u16x8 xv = *(const u16x8*)(x + (size_t)row * 512 + lane * 8);
    float f[8];
    float s = 0.f, s2 = 0.f;
    #pragma unroll
    for (int e = 0; e < 8; ++e) { f[e] = bf2f(xv[e]); s += f[e]; s2 += f[e] * f[e]; }
    #pragma unroll
    for (int o = 32; o > 0; o >>= 1) { s += __shfl_xor(s, o); s2 += __shfl_xor(s2, o); }
    float mean = s * (1.0f / 512.0f);
    float var  = s2 * (1.0f / 512.0f) - mean * mean;
    float rstd = rsqrtf(var + 1e-5f);

    float4 g0 = *(const float4*)(g + lane * 8);
    float4 g1 = *(const float4*)(g + lane * 8 + 4);
    float4 b0 = *(const float4*)(b + lane * 8);
    float4 b1 = *(const float4*)(b + lane * 8 + 4);
    float gg[8] = {g0.x, g0.y, g0.z, g0.w, g1.x, g1.y, g1.z, g1.w};
    float bb[8] = {b0.x, b0.y, b0.z, b0.w, b1.x, b1.y, b1.z, b1.w};
    u16x8 ov;
    #pragma unroll
    for (int e = 0; e < 8; ++e)
        ov[e] = f2bf((f[e] - mean) * rstd * gg[e] + bb[e]);
    *(u16x8*)(y + (size_t)row * 512 + lane * 8) = ov;
}

// -------- GEMM: C[M,N] = A[M,K](bf16) @ Bt[N,K](bf16)^T, 128x128 tile ------
// gll16 staging + LDS-staged coalesced epilogue + n-outer XCD swizzle.
// MODE 0: out0 = A@B0+bias0 (bf16), out1 = A@B1+bias1 (bf16)
// MODE 1: out0 = relu(A@B0+bias0) (bf16)
// MODE 2: outf = A@B0+bias0 + bf2f(residb) (fp32)
union SMem {
    struct { u16 As[128 * 32]; u16 Bs0[128 * 32]; u16 Bs1[128 * 32]; } st;  // 24 KB
    u16  eb16[128 * 136];    // 34816 B, stride 136 (16B-aligned rows, +8 pad)
    float ef32[64 * 132];    // 33792 B, stride 132 (16B-aligned rows)
};

__device__ __forceinline__ void epi_b16(
    const f32x4 acc[4][4], const float* __restrict__ bias, bool relu,
    u16* __restrict__ outp, SMem& sm, int m0, int n0,
    int wm, int wn, int l16, int quad, int tid)
{
    float bcol[4];
    #pragma unroll
    for (int j = 0; j < 4; ++j) bcol[j] = bias[n0 + wn * 64 + j * 16 + l16];
    #pragma unroll
    for (int i = 0; i < 4; ++i)
        #pragma unroll
        for (int j = 0; j < 4; ++j)
            #pragma unroll
            for (int r = 0; r < 4; ++r) {
                int lrow = wm * 64 + i * 16 + quad * 4 + r;
                int lcol = wn * 64 + j * 16 + l16;
                float v = acc[i][j][r] + bcol[j];
                if (relu) v = fmaxf(v, 0.f);
                sm.eb16[lrow * 136 + lcol] = f2bf(v);
            }
    __syncthreads();
    #pragma unroll
    for (int p = 0; p < 8; ++p) {
        int e0 = (p * 256 + tid) * 8;
        int row = e0 >> 7;
        int col = e0 & 127;
        u16x8 v = *(const u16x8*)&sm.eb16[row * 136 + col];
        *(u16x8*)&outp[(size_t)(m0 + row) * 512 + n0 + col] = v;
    }
    __syncthreads();
}

template <int MODE>
__global__ __launch_bounds__(256, 2) void gemm_bt(
    const u16* __restrict__ A, const u16* __restrict__ Bt0,
    const u16* __restrict__ Bt1, const float* __restrict__ bias0,
    const float* __restrict__ bias1, const u16* __restrict__ residb,
    void* __restrict__ out0v, u16* __restrict__ out1)
{
    constexpr int Kd = 512;
    __shared__ SMem sm;

    int bx = blockIdx.x;
    int m0 = (bx & 255) * 128;      // n-outer: blocks sharing A differ by 256 -> same XCD
    int n0 = (bx >> 8) * 128;
    int tid = threadIdx.x;
    int lane = tid & 63;
    int w = tid >> 6;
    int wm = w & 1, wn = w >> 1;
    int l16 = lane & 15;
    int quad = lane >> 4;

    f32x4 acc0[4][4] = {};
    f32x4 acc1[4][4] = {};

    for (int kt = 0; kt < Kd / 32; ++kt) {
        int k0 = kt * 32;
        #pragma unroll
        for (int i = 0; i < 2; ++i) {
            int ch = tid + i * 256;      // 0..511
            int row = ch >> 2;
            int ko = (ch & 3) * 8;
            gll16(A   + (size_t)(m0 + row) * Kd + k0 + ko, sm.st.As  + ch * 8);
            gll16(Bt0 + (size_t)(n0 + row) * Kd + k0 + ko, sm.st.Bs0 + ch * 8);
            if (MODE == 0)
                gll16(Bt1 + (size_t)(n0 + row) * Kd + k0 + ko, sm.st.Bs1 + ch * 8);
        }
        __syncthreads();

        bf16x8 af[4], bf0[4], bf1[4];
        #pragma unroll
        for (int i = 0; i < 4; ++i) {
            af[i]  = *(const bf16x8*)&sm.st.As [(wm * 64 + i * 16 + l16) * 32 + quad * 8];
            bf0[i] = *(const bf16x8*)&sm.st.Bs0[(wn * 64 + i * 16 + l16) * 32 + quad * 8];
            if (MODE == 0)
                bf1[i] = *(const bf16x8*)&sm.st.Bs1[(wn * 64 + i * 16 + l16) * 32 + quad * 8];
        }
        #pragma unroll
        for (int i = 0; i < 4; ++i)
            #pragma unroll
            for (int j = 0; j < 4; ++j) {
                acc0[i][j] = __builtin_amdgcn_mfma_f32_16x16x32_bf16(af[i], bf0[j], acc0[i][j], 0, 0, 0);
                if (MODE == 0)
                    acc1[i][j] = __builtin_amdgcn_mfma_f32_16x16x32_bf16(af[i], bf1[j], acc1[i][j], 0, 0, 0);
            }
        __syncthreads();
    }

    if (MODE == 0) {
        epi_b16(acc0, bias0, false, (u16*)out0v, sm, m0, n0, wm, wn, l16, quad, tid);
        epi_b16(acc1, bias1, false, out1,        sm, m0, n0, wm, wn, l16, quad, tid);
    } else if (MODE == 1) {
        epi_b16(acc0, bias0, true,  (u16*)out0v, sm, m0, n0, wm, wn, l16, quad, tid);
    } else {
        float* outf = (float*)out0v;
        float bcol[4];
        #pragma unroll
        for (int j = 0; j < 4; ++j) bcol[j] = bias0[n0 + wn * 64 + j * 16 + l16];
        #pragma unroll
        for (int half = 0; half < 2; ++half) {
            if (wm == half) {
                #pragma unroll
                for (int i = 0; i < 4; ++i)
                    #pragma unroll
                    for (int j = 0; j < 4; ++j)
                        #pragma unroll
                        for (int r = 0; r < 4; ++r) {
                            int lrow = i * 16 + quad * 4 + r;           // 0..63
                            int lcol = wn * 64 + j * 16 + l16;
                            sm.ef32[lrow * 132 + lcol] = acc0[i][j][r] + bcol[j];
                        }
            }
            __syncthreads();
            #pragma unroll
            for (int p = 0; p < 8; ++p) {
                int e0 = (p * 256 + tid) * 4;
                int row = e0 >> 7;
                int col = e0 & 127;
                float4 v = *(const float4*)&sm.ef32[row * 132 + col];
                size_t off = (size_t)(m0 + half * 64 + row) * 512 + n0 + col;
                u16x4 rb = *(const u16x4*)&residb[off];
                v.x += bf2f(rb[0]); v.y += bf2f(rb[1]);
                v.z += bf2f(rb[2]); v.w += bf2f(rb[3]);
                *(float4*)&outf[off] = v;
            }
            __syncthreads();
        }
    }
}

// -------- minGRU scan (chunked linear recurrence) --------------------------
__device__ __forceinline__ void gate_cv(u16 kraw, u16 hraw, float& c, float& v) {
    float kk = bf2f(kraw);
    float hh = bf2f(hraw);
    float z = 1.f / (1.f + __expf(-kk));   // sigmoid(k)
    c = 1.f / (1.f + __expf(kk));          // sigmoid(-k), saturation-safe
    float gg = (hh >= 0.f) ? (hh + 0.5f) : 1.f / (1.f + __expf(-hh));
    v = z * gg;
}

__global__ __launch_bounds__(256) void scanA(
    const u16* __restrict__ kb, const u16* __restrict__ hp,
    float* __restrict__ chC, float* __restrict__ chV)
{
    int gid = blockIdx.x * 256 + threadIdx.x;
    int h = gid & 511;
    int rest = gid >> 9;
    int b = rest & 3;
    int ch = rest >> 2;
    size_t base = ((size_t)(b * 8192 + ch * 128)) * 512 + h;
    float C = 1.f, V = 0.f;
    #pragma unroll 4
    for (int t = 0; t < 128; ++t) {
        float c, v;
        gate_cv(kb[base + (size_t)t * 512], hp[base + (size_t)t * 512], c, v);
        C *= c;
        V = fmaf(c, V, v);
    }
    int s = b * 512 + h;
    chC[ch * 2048 + s] = C;
    chV[ch * 2048 + s] = V;
}

__global__ __launch_bounds__(256) void scanB(
    const float* __restrict__ chC, const float* __restrict__ chV,
    float* __restrict__ hst)
{
    int s = blockIdx.x * 256 + threadIdx.x;
    float hcur = 0.5f;
    for (int ch = 0; ch < 64; ++ch) {
        hst[ch * 2048 + s] = hcur;
        hcur = chC[ch * 2048 + s] * hcur + chV[ch * 2048 + s];
    }
}

// x2 = bf16(x + h)
__global__ __launch_bounds__(256) void scanC(
    const u16* __restrict__ kb, const u16* __restrict__ hp,
    const float* __restrict__ hst, const float* __restrict__ x,
    u16* __restrict__ x2)
{
    int gid = blockIdx.x * 256 + threadIdx.x;
    int h = gid & 511;
    int rest = gid >> 9;
    int b = rest & 3;
    int ch = rest >> 2;
    size_t base = ((size_t)(b * 8192 + ch * 128)) * 512 + h;
    float hcur = hst[ch * 2048 + b * 512 + h];
    #pragma unroll 4
    for (int t = 0; t < 128; ++t) {
        float c, v;
        size_t off = base + (size_t)t * 512;
        gate_cv(kb[off], hp[off], c, v);
        hcur = fmaf(c, hcur, v);
        x2[off] = f2bf(x[off] + hcur);
    }
}

// ---------------------------------------------------------------------------
// ws layout (total 99.5 MiB, validated in round 4):
//   wt @ 0 (2 MiB) | hst @ 2M | chC @ 2.5M | chV @ 3M
//   a  @ 3.5 MiB (32 MiB bf16): LN1 out -> x2 (bf16 residual stream)
//   kb @ 35.5 MiB (32 MiB bf16): k preact -> FFN hidden
//   hp @ 67.5 MiB (32 MiB bf16): h~ preact -> LN2 out
extern "C" void kernel_launch(void* const* d_in, const int* in_sizes, int n_in,
                              void* d_out, int out_size, void* d_ws, size_t ws_size,
                              hipStream_t stream)
{
    const float* x    = (const float*)d_in[0];
    const float* ln1g = (const float*)d_in[1];
    const float* ln1b = (const float*)d_in[2];
    const float* Wz   = (const float*)d_in[3];
    const float* bz   = (const float*)d_in[4];
    const float* Wh   = (const float*)d_in[5];
    const float* bh   = (const float*)d_in[6];
    const float* ln2g = (const float*)d_in[7];
    const float* ln2b = (const float*)d_in[8];
    const float* W1   = (const float*)d_in[9];
    const float* b1   = (const float*)d_in[10];
    const float* W2   = (const float*)d_in[11];
    const float* b2   = (const float*)d_in[12];
    float* out = (float*)d_out;

    char* ws = (char*)d_ws;
    constexpr size_t MB = 1024 * 1024;
    u16* Wzt = (u16*)(ws);
    u16* Wht = Wzt + 262144;
    u16* W1t = Wzt + 524288;
    u16* W2t = Wzt + 786432;
    float* hst = (float*)(ws + 2 * MB);
    float* chC = (float*)(ws + 2 * MB + 512 * 1024);
    float* chV = (float*)(ws + 3 * MB);
    u16* a  = (u16*)(ws + 3 * MB + 512 * 1024);
    u16* kb = (u16*)(ws + 35 * MB + 512 * 1024);
    u16* hp = (u16*)(ws + 67 * MB + 512 * 1024);

    transpose4<<<1024, 256, 0, stream>>>(Wz, Wh, W1, W2, Wzt, Wht, W1t, W2t);
    // a = bf16(LN1(x))
    ln_f32<<<8192, 256, 0, stream>>>(x, ln1g, ln1b, a, 32768);
    // kb = k preact, hp = h~ preact
    gemm_bt<0><<<1024, 256, 0, stream>>>(a, Wzt, Wht, bz, bh, nullptr, kb, hp);
    scanA<<<512, 256, 0, stream>>>(kb, hp, chC, chV);
    scanB<<<8, 256, 0, stream>>>(chC, chV, hst);
    // a = bf16(x + h)  (residual stream; 'a' is dead after gemm0)
    scanC<<<512, 256, 0, stream>>>(kb, hp, hst, x, a);
    // hp = bf16(LN2(a))  (hp dead after scanC)
    ln_b16<<<8192, 256, 0, stream>>>(a, ln2g, ln2b, hp, 32768);
    // kb = relu(hp @ W1 + b1)  (kb dead after scanC)
    gemm_bt<1><<<1024, 256, 0, stream>>>(hp, W1t, nullptr, b1, nullptr, nullptr, kb, nullptr);
    // out = kb @ W2 + b2 + bf2f(a)  (fp32)
    gemm_bt<2><<<1024, 256, 0, stream>>>(kb, W2t, nullptr, b2, nullptr, a, out, nullptr);
}

// Round 6
// 399.249 us; speedup vs baseline: 1.3124x; 1.3124x over previous
//
#include <hip/hip_runtime.h>

typedef unsigned short u16;
typedef unsigned int u32;
typedef __bf16 bf16x8 __attribute__((ext_vector_type(8)));
typedef float f32x4 __attribute__((ext_vector_type(4)));
typedef u16 u16x8 __attribute__((ext_vector_type(8)));
typedef u16 u16x4 __attribute__((ext_vector_type(4)));

__device__ __forceinline__ u16 f2bf(float f) {
    union { float f; u32 i; } v; v.f = f;
    u32 x = v.i;
    u32 r = (x + 0x7fffu + ((x >> 16) & 1u)) >> 16;
    return (u16)r;
}
__device__ __forceinline__ float bf2f(u16 u) {
    union { u32 i; float f; } v; v.i = ((u32)u) << 16; return v.f;
}

__device__ __forceinline__ void gll16(const void* g, void* l) {
    __builtin_amdgcn_global_load_lds(
        (const __attribute__((address_space(1))) unsigned int*)(g),
        (__attribute__((address_space(3))) unsigned int*)(l),
        16, 0, 0);
}

// -------- weight transpose+convert: 4 matrices [512][512] fp32 -> bf16^T ---
__global__ __launch_bounds__(256) void transpose4(
    const float* __restrict__ s0, const float* __restrict__ s1,
    const float* __restrict__ s2, const float* __restrict__ s3,
    u16* __restrict__ d0, u16* __restrict__ d1,
    u16* __restrict__ d2, u16* __restrict__ d3)
{
    int bx = blockIdx.x;
    int mat = bx >> 8;
    int tile = bx & 255;
    int tx = (tile & 15) * 32;
    int ty = (tile >> 4) * 32;
    const float* src = (mat == 0) ? s0 : (mat == 1) ? s1 : (mat == 2) ? s2 : s3;
    u16* dst = (mat == 0) ? d0 : (mat == 1) ? d1 : (mat == 2) ? d2 : d3;

    __shared__ u16 tl[32][33];
    int col = threadIdx.x & 31;
    int r8  = threadIdx.x >> 5;
    #pragma unroll
    for (int k = 0; k < 4; ++k) {
        int rr = r8 + k * 8;
        tl[rr][col] = f2bf(src[(ty + rr) * 512 + tx + col]);
    }
    __syncthreads();
    #pragma unroll
    for (int k = 0; k < 4; ++k) {
        int rr = r8 + k * 8;
        dst[(tx + rr) * 512 + ty + col] = tl[col][rr];
    }
}

// -------- LayerNorm over H=512, one wave per row; out bf16 -----------------
__global__ __launch_bounds__(256) void ln_f32(
    const float* __restrict__ x, const float* __restrict__ g,
    const float* __restrict__ b, u16* __restrict__ y, int rows)
{
    int gid = blockIdx.x * blockDim.x + threadIdx.x;
    int row = gid >> 6;
    int lane = gid & 63;
    if (row >= rows) return;

    const float* xr = x + (size_t)row * 512 + lane * 8;
    float4 a0 = *(const float4*)xr;
    float4 a1 = *(const float4*)(xr + 4);
    float f[8] = {a0.x, a0.y, a0.z, a0.w, a1.x, a1.y, a1.z, a1.w};
    float s = 0.f, s2 = 0.f;
    #pragma unroll
    for (int e = 0; e < 8; ++e) { s += f[e]; s2 += f[e] * f[e]; }
    #pragma unroll
    for (int o = 32; o > 0; o >>= 1) { s += __shfl_xor(s, o); s2 += __shfl_xor(s2, o); }
    float mean = s * (1.0f / 512.0f);
    float var  = s2 * (1.0f / 512.0f) - mean * mean;
    float rstd = rsqrtf(var + 1e-5f);

    float4 g0 = *(const float4*)(g + lane * 8);
    float4 g1 = *(const float4*)(g + lane * 8 + 4);
    float4 b0 = *(const float4*)(b + lane * 8);
    float4 b1 = *(const float4*)(b + lane * 8 + 4);
    float gg[8] = {g0.x, g0.y, g0.z, g0.w, g1.x, g1.y, g1.z, g1.w};
    float bb[8] = {b0.x, b0.y, b0.z, b0.w, b1.x, b1.y, b1.z, b1.w};
    u16x8 ov;
    #pragma unroll
    for (int e = 0; e < 8; ++e)
        ov[e] = f2bf((f[e] - mean) * rstd * gg[e] + bb[e]);
    *(u16x8*)(y + (size_t)row * 512 + lane * 8) = ov;
}

__global__ __launch_bounds__(256) void ln_b16(
    const u16* __restrict__ x, const float* __restrict__ g,
    const float* __restrict__ b, u16* __restrict__ y, int rows)
{
    int gid = blockIdx.x * blockDim.x + threadIdx.x;
    int row = gid >> 6;
    int lane = gid & 63;
    if (row >= rows) return;

    u16x8 xv = *(const u16x8*)(x + (size_t)row * 512 + lane * 8);
    float f[8];
    float s = 0.f, s2 = 0.f;
    #pragma unroll
    for (int e = 0; e < 8; ++e) { f[e] = bf2f(xv[e]); s += f[e]; s2 += f[e] * f[e]; }
    #pragma unroll
    for (int o = 32; o > 0; o >>= 1) { s += __shfl_xor(s, o); s2 += __shfl_xor(s2, o); }
    float mean = s * (1.0f / 512.0f);
    float var  = s2 * (1.0f / 512.0f) - mean * mean;
    float rstd = rsqrtf(var + 1e-5f);

    float4 g0 = *(const float4*)(g + lane * 8);
    float4 g1 = *(const float4*)(g + lane * 8 + 4);
    float4 b0 = *(const float4*)(b + lane * 8);
    float4 b1 = *(const float4*)(b + lane * 8 + 4);
    float gg[8] = {g0.x, g0.y, g0.z, g0.w, g1.x, g1.y, g1.z, g1.w};
    float bb[8] = {b0.x, b0.y, b0.z, b0.w, b1.x, b1.y, b1.z, b1.w};
    u16x8 ov;
    #pragma unroll
    for (int e = 0; e < 8; ++e)
        ov[e] = f2bf((f[e] - mean) * rstd * gg[e] + bb[e]);
    *(u16x8*)(y + (size_t)row * 512 + lane * 8) = ov;
}

// -------- GEMM: C[M,N] = A[M,K](bf16) @ Bt[N,K](bf16)^T, 128x128 tile ------
// gll16 staging + OPERAND-SWAPPED MFMA (C^T in regs) -> vectorized direct
// epilogue, zero LDS after K-loop. n-outer XCD swizzle.
// Lane mapping after swap: m = l16, n = quad*4 + r (4 consecutive cols/lane).
// MODE 0: out0 = A@B0+bias0 (bf16), out1 = A@B1+bias1 (bf16)
// MODE 1: out0 = relu(A@B0+bias0) (bf16)
// MODE 2: outf = A@B0+bias0 + bf2f(residb) (fp32)
template <int MODE>
__global__ __launch_bounds__(256, 2) void gemm_bt(
    const u16* __restrict__ A, const u16* __restrict__ Bt0,
    const u16* __restrict__ Bt1, const float* __restrict__ bias0,
    const float* __restrict__ bias1, const u16* __restrict__ residb,
    void* __restrict__ out0v, u16* __restrict__ out1)
{
    constexpr int Kd = 512;
    __shared__ __align__(16) u16 As[128 * 32];
    __shared__ __align__(16) u16 Bs0[128 * 32];
    __shared__ __align__(16) u16 Bs1[(MODE == 0) ? 128 * 32 : 8];

    int bx = blockIdx.x;
    int m0 = (bx & 255) * 128;      // n-outer: blocks sharing A differ by 256 -> same XCD
    int n0 = (bx >> 8) * 128;
    int tid = threadIdx.x;
    int lane = tid & 63;
    int w = tid >> 6;
    int wm = w & 1, wn = w >> 1;
    int l16 = lane & 15;
    int quad = lane >> 4;

    f32x4 acc0[4][4] = {};
    f32x4 acc1[4][4] = {};

    for (int kt = 0; kt < Kd / 32; ++kt) {
        int k0 = kt * 32;
        #pragma unroll
        for (int i = 0; i < 2; ++i) {
            int ch = tid + i * 256;      // 0..511
            int row = ch >> 2;
            int ko = (ch & 3) * 8;
            gll16(A   + (size_t)(m0 + row) * Kd + k0 + ko, As  + ch * 8);
            gll16(Bt0 + (size_t)(n0 + row) * Kd + k0 + ko, Bs0 + ch * 8);
            if (MODE == 0)
                gll16(Bt1 + (size_t)(n0 + row) * Kd + k0 + ko, Bs1 + ch * 8);
        }
        __syncthreads();

        bf16x8 af[4], bf0[4], bf1[4];
        #pragma unroll
        for (int i = 0; i < 4; ++i) {
            af[i]  = *(const bf16x8*)&As [(wm * 64 + i * 16 + l16) * 32 + quad * 8];
            bf0[i] = *(const bf16x8*)&Bs0[(wn * 64 + i * 16 + l16) * 32 + quad * 8];
            if (MODE == 0)
                bf1[i] = *(const bf16x8*)&Bs1[(wn * 64 + i * 16 + l16) * 32 + quad * 8];
        }
        // Operand swap: D = B_frag * A_frag -> D holds C^T fragments.
        #pragma unroll
        for (int i = 0; i < 4; ++i)
            #pragma unroll
            for (int j = 0; j < 4; ++j) {
                acc0[i][j] = __builtin_amdgcn_mfma_f32_16x16x32_bf16(bf0[j], af[i], acc0[i][j], 0, 0, 0);
                if (MODE == 0)
                    acc1[i][j] = __builtin_amdgcn_mfma_f32_16x16x32_bf16(bf1[j], af[i], acc1[i][j], 0, 0, 0);
            }
        __syncthreads();
    }

    // Epilogue: lane covers (m = m0+wm*64+i*16+l16, n = n0+wn*64+j*16+quad*4 ..+3)
    #pragma unroll
    for (int j = 0; j < 4; ++j) {
        int nb = n0 + wn * 64 + j * 16 + quad * 4;
        float4 bv = *(const float4*)&bias0[nb];
        float4 bv1 = (MODE == 0) ? *(const float4*)&bias1[nb] : float4{0,0,0,0};
        #pragma unroll
        for (int i = 0; i < 4; ++i) {
            int m = m0 + wm * 64 + i * 16 + l16;
            size_t off = (size_t)m * 512 + nb;
            float v0 = acc0[i][j][0] + bv.x;
            float v1 = acc0[i][j][1] + bv.y;
            float v2 = acc0[i][j][2] + bv.z;
            float v3 = acc0[i][j][3] + bv.w;
            if (MODE == 1) {
                v0 = fmaxf(v0, 0.f); v1 = fmaxf(v1, 0.f);
                v2 = fmaxf(v2, 0.f); v3 = fmaxf(v3, 0.f);
            }
            if (MODE == 2) {
                u16x4 rb = *(const u16x4*)&residb[off];
                float4 o = {v0 + bf2f(rb[0]), v1 + bf2f(rb[1]),
                            v2 + bf2f(rb[2]), v3 + bf2f(rb[3])};
                *(float4*)&((float*)out0v)[off] = o;
            } else {
                u16x4 o = {f2bf(v0), f2bf(v1), f2bf(v2), f2bf(v3)};
                *(u16x4*)&((u16*)out0v)[off] = o;
                if (MODE == 0) {
                    u16x4 o1 = {f2bf(acc1[i][j][0] + bv1.x), f2bf(acc1[i][j][1] + bv1.y),
                                f2bf(acc1[i][j][2] + bv1.z), f2bf(acc1[i][j][3] + bv1.w)};
                    *(u16x4*)&out1[off] = o1;
                }
            }
        }
    }
}

// -------- minGRU scan (chunked linear recurrence) --------------------------
__device__ __forceinline__ void gate_cv(u16 kraw, u16 hraw, float& c, float& v) {
    float kk = bf2f(kraw);
    float hh = bf2f(hraw);
    float z = 1.f / (1.f + __expf(-kk));   // sigmoid(k)
    c = 1.f / (1.f + __expf(kk));          // sigmoid(-k), saturation-safe
    float gg = (hh >= 0.f) ? (hh + 0.5f) : 1.f / (1.f + __expf(-hh));
    v = z * gg;
}

__global__ __launch_bounds__(256) void scanA(
    const u16* __restrict__ kb, const u16* __restrict__ hp,
    float* __restrict__ chC, float* __restrict__ chV)
{
    int gid = blockIdx.x * 256 + threadIdx.x;
    int h = gid & 511;
    int rest = gid >> 9;
    int b = rest & 3;
    int ch = rest >> 2;
    size_t base = ((size_t)(b * 8192 + ch * 128)) * 512 + h;
    float C = 1.f, V = 0.f;
    #pragma unroll 4
    for (int t = 0; t < 128; ++t) {
        float c, v;
        gate_cv(kb[base + (size_t)t * 512], hp[base + (size_t)t * 512], c, v);
        C *= c;
        V = fmaf(c, V, v);
    }
    int s = b * 512 + h;
    chC[ch * 2048 + s] = C;
    chV[ch * 2048 + s] = V;
}

__global__ __launch_bounds__(256) void scanB(
    const float* __restrict__ chC, const float* __restrict__ chV,
    float* __restrict__ hst)
{
    int s = blockIdx.x * 256 + threadIdx.x;
    float hcur = 0.5f;
    for (int ch = 0; ch < 64; ++ch) {
        hst[ch * 2048 + s] = hcur;
        hcur = chC[ch * 2048 + s] * hcur + chV[ch * 2048 + s];
    }
}

// x2 = bf16(x + h)
__global__ __launch_bounds__(256) void scanC(
    const u16* __restrict__ kb, const u16* __restrict__ hp,
    const float* __restrict__ hst, const float* __restrict__ x,
    u16* __restrict__ x2)
{
    int gid = blockIdx.x * 256 + threadIdx.x;
    int h = gid & 511;
    int rest = gid >> 9;
    int b = rest & 3;
    int ch = rest >> 2;
    size_t base = ((size_t)(b * 8192 + ch * 128)) * 512 + h;
    float hcur = hst[ch * 2048 + b * 512 + h];
    #pragma unroll 4
    for (int t = 0; t < 128; ++t) {
        float c, v;
        size_t off = base + (size_t)t * 512;
        gate_cv(kb[off], hp[off], c, v);
        hcur = fmaf(c, hcur, v);
        x2[off] = f2bf(x[off] + hcur);
    }
}

// ---------------------------------------------------------------------------
// ws layout (total 99.5 MiB, validated):
//   wt @ 0 (2 MiB) | hst @ 2M | chC @ 2.5M | chV @ 3M
//   a  @ 3.5 MiB (32 MiB bf16): LN1 out -> x2 (bf16 residual stream)
//   kb @ 35.5 MiB (32 MiB bf16): k preact -> FFN hidden
//   hp @ 67.5 MiB (32 MiB bf16): h~ preact -> LN2 out
extern "C" void kernel_launch(void* const* d_in, const int* in_sizes, int n_in,
                              void* d_out, int out_size, void* d_ws, size_t ws_size,
                              hipStream_t stream)
{
    const float* x    = (const float*)d_in[0];
    const float* ln1g = (const float*)d_in[1];
    const float* ln1b = (const float*)d_in[2];
    const float* Wz   = (const float*)d_in[3];
    const float* bz   = (const float*)d_in[4];
    const float* Wh   = (const float*)d_in[5];
    const float* bh   = (const float*)d_in[6];
    const float* ln2g = (const float*)d_in[7];
    const float* ln2b = (const float*)d_in[8];
    const float* W1   = (const float*)d_in[9];
    const float* b1   = (const float*)d_in[10];
    const float* W2   = (const float*)d_in[11];
    const float* b2   = (const float*)d_in[12];
    float* out = (float*)d_out;

    char* ws = (char*)d_ws;
    constexpr size_t MB = 1024 * 1024;
    u16* Wzt = (u16*)(ws);
    u16* Wht = Wzt + 262144;
    u16* W1t = Wzt + 524288;
    u16* W2t = Wzt + 786432;
    float* hst = (float*)(ws + 2 * MB);
    float* chC = (float*)(ws + 2 * MB + 512 * 1024);
    float* chV = (float*)(ws + 3 * MB);
    u16* a  = (u16*)(ws + 3 * MB + 512 * 1024);
    u16* kb = (u16*)(ws + 35 * MB + 512 * 1024);
    u16* hp = (u16*)(ws + 67 * MB + 512 * 1024);

    transpose4<<<1024, 256, 0, stream>>>(Wz, Wh, W1, W2, Wzt, Wht, W1t, W2t);
    // a = bf16(LN1(x))
    ln_f32<<<8192, 256, 0, stream>>>(x, ln1g, ln1b, a, 32768);
    // kb = k preact, hp = h~ preact
    gemm_bt<0><<<1024, 256, 0, stream>>>(a, Wzt, Wht, bz, bh, nullptr, kb, hp);
    scanA<<<512, 256, 0, stream>>>(kb, hp, chC, chV);
    scanB<<<8, 256, 0, stream>>>(chC, chV, hst);
    // a = bf16(x + h)  (residual stream; 'a' dead after gemm0)
    scanC<<<512, 256, 0, stream>>>(kb, hp, hst, x, a);
    // hp = bf16(LN2(a))  (hp dead after scanC)
    ln_b16<<<8192, 256, 0, stream>>>(a, ln2g, ln2b, hp, 32768);
    // kb = relu(hp @ W1 + b1)  (kb dead after scanC)
    gemm_bt<1><<<1024, 256, 0, stream>>>(hp, W1t, nullptr, b1, nullptr, nullptr, kb, nullptr);
    // out = kb @ W2 + b2 + bf2f(a)  (fp32)
    gemm_bt<2><<<1024, 256, 0, stream>>>(kb, W2t, nullptr, b2, nullptr, a, out, nullptr);
}